// Round 8
// baseline (173.575 us; speedup 1.0000x reference)
//
#include <hip/hip_runtime.h>
#include <math.h>

#define VV 8192
#define DD 768
#define NDMAX 256

typedef __attribute__((ext_vector_type(8))) short bf16x8;
typedef __attribute__((ext_vector_type(4))) float f32x4;

// RNE float -> bf16 bits
__device__ inline ushort f2bf(float f) {
    uint u = __float_as_uint(f);
    uint r = (u + 0x7fffu + ((u >> 16) & 1u)) >> 16;
    return (ushort)r;
}
__device__ inline float bf2f(ushort h) { return __uint_as_float(((uint)h) << 16); }

__device__ inline void gload16(const ushort* g, ushort* l) {
    __builtin_amdgcn_global_load_lds(
        (const __attribute__((address_space(1))) void*)g,
        (__attribute__((address_space(3))) void*)l, 16, 0, 0);
}
#define BAR() asm volatile("s_barrier" ::: "memory")
#define SCHED0() __builtin_amdgcn_sched_barrier(0)
#define LGKM0() asm volatile("s_waitcnt lgkmcnt(0)" ::: "memory")
#define LGKM8() asm volatile("s_waitcnt lgkmcnt(8)" ::: "memory")
#define VM6() asm volatile("s_waitcnt vmcnt(6)" ::: "memory")
#define VM0() asm volatile("s_waitcnt vmcnt(0)" ::: "memory")

// ---------------------------------------------------------------------------
// k_normpack: L2-normalize rows (fp64 norm accum) -> xh/xl (bf16 hi/lo split)
// + norms[r]. Also zeroes g and rc.
// ---------------------------------------------------------------------------
__global__ __launch_bounds__(256) void k_normpack(const float* __restrict__ t,
                                                  float* __restrict__ norms,
                                                  ushort* __restrict__ xh,
                                                  ushort* __restrict__ xl,
                                                  double* __restrict__ g,
                                                  float* __restrict__ rc) {
    int r = blockIdx.x;
    const float* tr = t + (size_t)r * DD;
    int tid = threadIdx.x;
    float v0 = tr[tid], v1 = tr[tid + 256], v2 = tr[tid + 512];
    double s = (double)v0 * v0 + (double)v1 * v1 + (double)v2 * v2;
#pragma unroll
    for (int o = 32; o > 0; o >>= 1) s += __shfl_down(s, o, 64);
    __shared__ double wsum[4];
    int lane = tid & 63, w = tid >> 6;
    if (lane == 0) wsum[w] = s;
    __syncthreads();
    double tot = wsum[0] + wsum[1] + wsum[2] + wsum[3];
    float norm = fmaxf((float)sqrt(tot), 1e-12f);
    if (tid == 0) {
        norms[r] = norm;
        rc[r] = 0.f;
        if (r < DD) g[r] = 0.0;
    }
    size_t base = (size_t)r * DD;
#pragma unroll
    for (int q = 0; q < 3; ++q) {
        int k = tid + q * 256;
        float v = (q == 0 ? v0 : (q == 1 ? v1 : v2)) / norm;
        ushort h = f2bf(v);
        xh[base + k] = h;
        xl[base + k] = f2bf(v - bf2f(h));
    }
}

// ---------------------------------------------------------------------------
// k_colsum: g[k] = sum over rows of fp32(t[r][k]/norm[r]), fp64 accum.
// ---------------------------------------------------------------------------
__global__ __launch_bounds__(256) void k_colsum(const float* __restrict__ t,
                                                const float* __restrict__ norms,
                                                double* __restrict__ g) {
    int k = threadIdx.x;
    int r0 = blockIdx.x * 32;
    double s0 = 0.0, s1 = 0.0, s2 = 0.0;
    for (int r = r0; r < r0 + 32; ++r) {
        const float* tr = t + (size_t)r * DD;
        float nrm = norms[r];
        s0 += (double)(tr[k] / nrm);
        s1 += (double)(tr[k + 256] / nrm);
        s2 += (double)(tr[k + 512] / nrm);
    }
    atomicAdd(&g[k], s0);
    atomicAdd(&g[k + 256], s1);
    atomicAdd(&g[k + 512], s2);
}

// ---------------------------------------------------------------------------
// k_mean: mnum[r] = x_r.g - x_r.x_r (fp64); dd[r] = x_r.x_r.
// Exact mean path -- numerically deadly, do not approximate.
// ---------------------------------------------------------------------------
__global__ __launch_bounds__(256) void k_mean(const float* __restrict__ t,
                                              const float* __restrict__ norms,
                                              const double* __restrict__ g,
                                              double* __restrict__ mnum,
                                              double* __restrict__ dd) {
    int r = blockIdx.x * 4 + (threadIdx.x >> 6);
    int lane = threadIdx.x & 63;
    const float* tr = t + (size_t)r * DD;
    float nrm = norms[r];
    double xg = 0.0, xx = 0.0;
#pragma unroll
    for (int k = lane; k < DD; k += 64) {
        float xf = tr[k] / nrm;
        double xv = (double)xf;
        xg += xv * g[k];
        xx += xv * xv;
    }
#pragma unroll
    for (int o = 32; o > 0; o >>= 1) {
        xg += __shfl_down(xg, o, 64);
        xx += __shfl_down(xx, o, 64);
    }
    if (lane == 0) {
        mnum[r] = xg - xx;
        dd[r] = xx;
    }
}

// ---------------------------------------------------------------------------
// k_select: deterministic row-sorted compaction of danger rows
// (|mean_neg+eps| < 1e-5).
// ---------------------------------------------------------------------------
__global__ __launch_bounds__(256) void k_select(const double* __restrict__ mnum,
                                                int* __restrict__ dlist) {
    __shared__ int cnts[256];
    int tid = threadIdx.x;
    dlist[tid] = -1;
    int r0 = tid * 32;
    int c = 0;
    for (int i = 0; i < 32; ++i) {
        double md = fabs(mnum[r0 + i] / 8191.0 + 1e-6);
        if (md < 1e-5) ++c;
    }
    cnts[tid] = c;
    __syncthreads();
    int pre = 0;
    for (int i = 0; i < tid; ++i) pre += cnts[i];
    for (int i = 0; i < 32; ++i) {
        int r = r0 + i;
        double md = fabs(mnum[r] / 8191.0 + 1e-6);
        if (md < 1e-5) {
            if (pre < NDMAX) dlist[pre] = r;
            ++pre;
        }
    }
}

// ---------------------------------------------------------------------------
// MFMA/LD helpers for the 8-phase kloop
// ---------------------------------------------------------------------------
__device__ __forceinline__ void lda8(bf16x8 (&av)[8], const ushort* base, int aoff) {
#pragma unroll
    for (int f = 0; f < 4; ++f)
#pragma unroll
        for (int h = 0; h < 2; ++h)
            av[f * 2 + h] = *(const bf16x8*)(base + f * 512 + h * 4096 + aoff);
}
__device__ __forceinline__ void ldb4(bf16x8 (&bv)[4], const ushort* base, int boff) {
#pragma unroll
    for (int n = 0; n < 2; ++n)
#pragma unroll
        for (int h = 0; h < 2; ++h)
            bv[n * 2 + h] = *(const bf16x8*)(base + n * 512 + h * 4096 + boff);
}
__device__ __forceinline__ void mfma16(f32x4 (&aq)[4][2], const bf16x8 (&av)[8],
                                       const bf16x8 (&bv)[4]) {
    __builtin_amdgcn_s_setprio(1);
#pragma unroll
    for (int f = 0; f < 4; ++f)
#pragma unroll
        for (int n = 0; n < 2; ++n)
#pragma unroll
            for (int h = 0; h < 2; ++h)
                aq[f][n] = __builtin_amdgcn_mfma_f32_16x16x32_bf16(
                    av[f * 2 + h], bv[n * 2 + h], aq[f][n], 0, 0, 0);
    __builtin_amdgcn_s_setprio(0);
}

// ---------------------------------------------------------------------------
// k_cube: 256x256 bf16 MFMA pass, m201-style 8-phase schedule (2 K-tiles per
// iteration). Phase = block-wide C-quadrant (A-half x B-half): all 8 waves
// read the same halves in a phase, so each half is free 1 phase after its
// last read -> rotating half-buffer staging, 1 half (2 gloads) per phase,
// 6-7 phases ahead of use; vmcnt(6) only at phases 4/8 (3 halves in flight).
// Quadrant order (0,0),(0,1),(1,1),(1,0) with A0/B0 register-held ->
// ds_reads 12/4/8/0 per phase. setprio around MFMA clusters.
// LDS: per tile-buf, A/B halves [2 ksub][128][32] bf16, slot swizzle
// s ^= ((row>>3)&1)<<1 (st_16x32-equivalent, bank-floor), staged via
// global_load_lds w=16 with pre-swizzled per-lane source, linear dest.
//  - bids 0..95: strip-partial (seg, colchunk): danger rows x 256 cols,
//    store partial S into Sb (no cube).
//  - bids 96..607: big triangle tiles (hh), XCD-swizzled, cube+row/col sums.
//  - bids 608..671: quarter tiles of the last 16 triangle tiles (old loop).
// ---------------------------------------------------------------------------
__global__ __launch_bounds__(512, 2) void k_cube(const ushort* __restrict__ xh,
                                                 const ushort* __restrict__ xl,
                                                 const int* __restrict__ dlist,
                                                 float* __restrict__ Sb,
                                                 float* __restrict__ rc) {
    __shared__ ushort LDS[65536];  // 128 KiB

    const int bid = blockIdx.x;
    const int tid = threadIdx.x;
    const int lane = tid & 63;
    const int wid = tid >> 6;
    const int l15 = lane & 15, li4 = lane >> 4;

    if (bid >= 608) {
        // ---- quarter tile: 128x128, K=768 (hh only) -- unchanged path ----
        const int swzrd = ((li4 ^ ((l15 >> 1) & 3)) << 3);
        const int qid = bid - 608;
        int wg = 512 + (qid >> 2), q = qid & 3;
        int bi = 0, rem = wg;
        while (rem >= 32 - bi) { rem -= 32 - bi; ++bi; }
        const int bj = bi + rem;
        const int gr = bi * 2 + (q >> 1), gc = bj * 2 + (q & 1);
        if (gc < gr) return;
        const int R0 = gr * 128, C0 = gc * 128;
        const int wm = wid >> 2, wn = wid & 3;
        const int aoff = (wm * 64 + l15) * 32 + swzrd;
        const int boff = (wn * 32 + l15) * 32 + swzrd;
        const int sl = ((tid & 3) ^ ((tid >> 3) & 3)) * 8;
        const int gA0 = (R0 + (tid >> 2)) * DD + sl;
        const int gB0 = (C0 + (tid >> 2)) * DD + sl;
        const int ld0 = tid * 8;

        f32x4 acc[4][2];
#pragma unroll
        for (int f = 0; f < 4; ++f)
#pragma unroll
            for (int n = 0; n < 2; ++n) acc[f][n] = (f32x4){0.f, 0.f, 0.f, 0.f};

        gload16(xh + gA0, LDS + ld0);
        gload16(xh + gB0, LDS + 8192 + ld0);
        gload16(xh + gA0 + 32, LDS + 4096 + ld0);
        gload16(xh + gB0 + 32, LDS + 12288 + ld0);
        VM0(); SCHED0(); BAR();

        for (int t = 0; t < 12; ++t) {
            const int cur = t & 1;
            ushort* A0 = LDS + cur * 16384;
            ushort* A1 = A0 + 4096;
            ushort* B0 = A0 + 8192;
            ushort* B1 = A0 + 12288;
            ushort* nA0 = LDS + (cur ^ 1) * 16384;
            const bool st = (t < 11);
            const int c1 = (t + 1) * 64;

            if (st) {
                gload16(xh + gA0 + c1, nA0 + ld0);
                gload16(xh + gB0 + c1, nA0 + 8192 + ld0);
                gload16(xh + gA0 + c1 + 32, nA0 + 4096 + ld0);
                gload16(xh + gB0 + c1 + 32, nA0 + 12288 + ld0);
            }
            SCHED0();
            bf16x8 av0[4], av1[4], bv0[2], bv1[2];
#pragma unroll
            for (int f = 0; f < 4; ++f) {
                av0[f] = *(const bf16x8*)(A0 + aoff + f * 512);
                av1[f] = *(const bf16x8*)(A1 + aoff + f * 512);
            }
#pragma unroll
            for (int n = 0; n < 2; ++n) {
                bv0[n] = *(const bf16x8*)(B0 + boff + n * 512);
                bv1[n] = *(const bf16x8*)(B1 + boff + n * 512);
            }
            __builtin_amdgcn_s_setprio(1);
#pragma unroll
            for (int f = 0; f < 4; ++f)
#pragma unroll
                for (int n = 0; n < 2; ++n)
                    acc[f][n] = __builtin_amdgcn_mfma_f32_16x16x32_bf16(av0[f], bv0[n], acc[f][n], 0, 0, 0);
#pragma unroll
            for (int f = 0; f < 4; ++f)
#pragma unroll
                for (int n = 0; n < 2; ++n)
                    acc[f][n] = __builtin_amdgcn_mfma_f32_16x16x32_bf16(av1[f], bv1[n], acc[f][n], 0, 0, 0);
            __builtin_amdgcn_s_setprio(0);
            VM0(); SCHED0(); BAR();
        }

        const bool dblk = (gr == gc);
        float rsum[4][4], csum[2];
#pragma unroll
        for (int n = 0; n < 2; ++n) csum[n] = 0.f;
#pragma unroll
        for (int f = 0; f < 4; ++f)
#pragma unroll
            for (int r = 0; r < 4; ++r) rsum[f][r] = 0.f;
#pragma unroll
        for (int f = 0; f < 4; ++f)
#pragma unroll
            for (int n = 0; n < 2; ++n)
#pragma unroll
                for (int r = 0; r < 4; ++r) {
                    float s = acc[f][n][r];
                    float c = s * s * s;
                    int ri = wm * 64 + f * 16 + li4 * 4 + r;
                    int cj = wn * 32 + n * 16 + l15;
                    if (dblk && ri == cj) c = 0.f;
                    rsum[f][r] += c;
                    csum[n] += c;
                }
#pragma unroll
        for (int o = 1; o < 16; o <<= 1)
#pragma unroll
            for (int f = 0; f < 4; ++f)
#pragma unroll
                for (int r = 0; r < 4; ++r)
                    rsum[f][r] += __shfl_xor(rsum[f][r], o, 64);
        if (l15 == 0) {
#pragma unroll
            for (int f = 0; f < 4; ++f)
#pragma unroll
                for (int r = 0; r < 4; ++r)
                    atomicAdd(&rc[R0 + wm * 64 + f * 16 + li4 * 4 + r], rsum[f][r]);
        }
        if (!dblk) {
#pragma unroll
            for (int o = 16; o < 64; o <<= 1)
#pragma unroll
                for (int n = 0; n < 2; ++n) csum[n] += __shfl_xor(csum[n], o, 64);
            if (li4 == 0) {
#pragma unroll
                for (int n = 0; n < 2; ++n)
                    atomicAdd(&rc[C0 + wn * 32 + n * 16 + l15], csum[n]);
            }
        }
        return;
    }

    // ---- shared 256x256 path: strip-partial (bid<96) or big tile ----
    const bool strip = (bid < 96);
    int bi = 0, bj = 0, seg = 0, cc = 0;
    if (strip) {
        seg = bid >> 5;
        cc = bid & 31;
    } else {
        const int idx = bid - 96;
        int wg = (idx & 7) * 64 + (idx >> 3);
        int rem = wg;
        while (rem >= 32 - bi) { rem -= 32 - bi; ++bi; }
        bj = bi + rem;
    }
    const int wq = wid >> 2, wc = wid & 3;
    const int aswz = (li4 ^ (((l15 >> 3) & 1) << 1)) * 8;
    const int aoff = (wq * 64 + l15) * 32 + aswz;
    const int boff = (wc * 32 + l15) * 32 + aswz;

    // staging descriptors (2 loads/thread per half)
    int ldst[2], koff[2], row7[2];
#pragma unroll
    for (int j = 0; j < 2; ++j) {
        int li = tid + j * 512;
        row7[j] = (li >> 2) & 127;
        koff[j] = (li >> 9) * 32 + (((li & 3) ^ (((li >> 5) & 1) << 1))) * 8;
        ldst[j] = li * 8;
    }
    int asrc0[2], asrc1[2], bsrc0[2], bsrc1[2];
    const int bt = strip ? cc : bj;
    const ushort *XA, *XB;
    if (strip) {
        XA = (seg == 1) ? xl : xh;
        XB = (seg == 2) ? xl : xh;
    } else {
        XA = xh; XB = xh;
    }
#pragma unroll
    for (int j = 0; j < 2; ++j) {
        int a0, a1;
        if (strip) {
            a0 = dlist[row7[j]];        if (a0 < 0) a0 = 0;
            a1 = dlist[128 + row7[j]];  if (a1 < 0) a1 = 0;
        } else {
            a0 = bi * 256 + row7[j];
            a1 = bi * 256 + 128 + row7[j];
        }
        asrc0[j] = a0 * DD + koff[j];
        asrc1[j] = a1 * DD + koff[j];
        bsrc0[j] = (bt * 256 + row7[j]) * DD + koff[j];
        bsrc1[j] = (bt * 256 + 128 + row7[j]) * DD + koff[j];
    }

#define STG(X, SRC, DOFF, KT)                                   \
    do {                                                        \
        gload16((X) + SRC[0] + (KT) * 64, LDS + (DOFF) + ldst[0]); \
        gload16((X) + SRC[1] + (KT) * 64, LDS + (DOFF) + ldst[1]); \
    } while (0)

    // LDS half offsets (ushort units): A(buf,mh)=buf*16384+mh*8192;
    // B(buf,nh)=32768+buf*16384+nh*8192.
    f32x4 acc[4][4][2];  // [quad][f][n]
#pragma unroll
    for (int q = 0; q < 4; ++q)
#pragma unroll
        for (int f = 0; f < 4; ++f)
#pragma unroll
            for (int n = 0; n < 2; ++n) acc[q][f][n] = (f32x4){0.f, 0.f, 0.f, 0.f};

    // prologue: A0(0),B0(0),B1(0),A1(0),B0(1),A0(1),B1(1); A1(1) at p1 of i=0
    STG(XA, asrc0, 0, 0);
    STG(XB, bsrc0, 32768, 0);
    STG(XB, bsrc1, 40960, 0);
    STG(XA, asrc1, 8192, 0);
    STG(XB, bsrc0, 49152, 1);
    STG(XA, asrc0, 16384, 1);
    STG(XB, bsrc1, 57344, 1);
    VM6(); SCHED0(); BAR();

    bf16x8 av0[8], av1[8], bv0[4], bv1[4];
#pragma unroll 1
    for (int i = 0; i < 6; ++i) {
        const int kt1 = 2 * i + 1, kt2 = 2 * i + 2, kt3 = 2 * i + 3;
        const bool s2 = (i < 5), s3 = (i < 4);
        // ---- p1: tile 2i quad(0,0); stage A1(2i+1)->buf1.A1
        lda8(av0, LDS + 0, aoff);
        ldb4(bv0, LDS + 32768, boff);
        STG(XA, asrc1, 24576, kt1);
        LGKM8(); SCHED0(); BAR();
        LGKM0(); SCHED0();
        mfma16(acc[0], av0, bv0);
        SCHED0(); BAR();
        // ---- p2: quad(0,1); stage B0(2i+2)->buf0.B0
        ldb4(bv1, LDS + 40960, boff);
        if (s2) STG(XB, bsrc0, 32768, kt2);
        SCHED0(); BAR();
        LGKM0(); SCHED0();
        mfma16(acc[1], av0, bv1);
        SCHED0(); BAR();
        // ---- p3: quad(1,1); stage A0(2i+2)->buf0.A0
        lda8(av1, LDS + 8192, aoff);
        if (s2) STG(XA, asrc0, 0, kt2);
        SCHED0(); BAR();
        LGKM0(); SCHED0();
        mfma16(acc[2], av1, bv1);
        SCHED0(); BAR();
        // ---- p4: quad(1,0) (regs only); stage B1(2i+2)->buf0.B1; vmcnt
        if (s2) STG(XB, bsrc1, 40960, kt2);
        SCHED0(); BAR();
        mfma16(acc[3], av1, bv0);
        if (s2) { VM6(); } else { VM0(); }
        SCHED0(); BAR();
        // ---- p5: tile 2i+1 quad(0,0); stage A1(2i+2)->buf0.A1
        lda8(av0, LDS + 16384, aoff);
        ldb4(bv0, LDS + 49152, boff);
        if (s2) STG(XA, asrc1, 8192, kt2);
        LGKM8(); SCHED0(); BAR();
        LGKM0(); SCHED0();
        mfma16(acc[0], av0, bv0);
        SCHED0(); BAR();
        // ---- p6: quad(0,1); stage B0(2i+3)->buf1.B0
        ldb4(bv1, LDS + 57344, boff);
        if (s3) STG(XB, bsrc0, 49152, kt3);
        SCHED0(); BAR();
        LGKM0(); SCHED0();
        mfma16(acc[1], av0, bv1);
        SCHED0(); BAR();
        // ---- p7: quad(1,1); stage A0(2i+3)->buf1.A0
        lda8(av1, LDS + 24576, aoff);
        if (s3) STG(XA, asrc0, 16384, kt3);
        SCHED0(); BAR();
        LGKM0(); SCHED0();
        mfma16(acc[2], av1, bv1);
        SCHED0(); BAR();
        // ---- p8: quad(1,0); stage B1(2i+3)->buf1.B1; vmcnt
        if (s3) STG(XB, bsrc1, 57344, kt3);
        SCHED0(); BAR();
        mfma16(acc[3], av1, bv0);
        if (s2) { VM6(); }
        SCHED0(); BAR();
    }
#undef STG

    // quad -> (mh, nh): 0=(0,0) 1=(0,1) 2=(1,1) 3=(1,0)
    const int mhq[4] = {0, 0, 1, 1}, nhq[4] = {0, 1, 1, 0};

    if (strip) {
        // store partial S (f32) by danger slot; finish pass cubes later
#pragma unroll
        for (int q = 0; q < 4; ++q)
#pragma unroll
            for (int f = 0; f < 4; ++f)
#pragma unroll
                for (int n = 0; n < 2; ++n)
#pragma unroll
                    for (int r = 0; r < 4; ++r) {
                        int arow = mhq[q] * 128 + wq * 64 + f * 16 + li4 * 4 + r;
                        int col = cc * 256 + nhq[q] * 128 + wc * 32 + n * 16 + l15;
                        Sb[((size_t)(seg * 256 + arow) << 13) + col] = acc[q][f][n][r];
                    }
        return;
    }

    // big-tile epilogue: cube, skip diag, row + col (symmetry) sums
    const bool dblk = (bi == bj);
    float rsum[2][4][4], csum[2][2];
#pragma unroll
    for (int m = 0; m < 2; ++m)
#pragma unroll
        for (int f = 0; f < 4; ++f)
#pragma unroll
            for (int r = 0; r < 4; ++r) rsum[m][f][r] = 0.f;
#pragma unroll
    for (int n2 = 0; n2 < 2; ++n2)
#pragma unroll
        for (int n = 0; n < 2; ++n) csum[n2][n] = 0.f;
#pragma unroll
    for (int q = 0; q < 4; ++q)
#pragma unroll
        for (int f = 0; f < 4; ++f)
#pragma unroll
            for (int n = 0; n < 2; ++n)
#pragma unroll
                for (int r = 0; r < 4; ++r) {
                    float s = acc[q][f][n][r];
                    float c = s * s * s;
                    int ri = mhq[q] * 128 + wq * 64 + f * 16 + li4 * 4 + r;
                    int cj = nhq[q] * 128 + wc * 32 + n * 16 + l15;
                    if (dblk && ri == cj) c = 0.f;
                    rsum[mhq[q]][f][r] += c;
                    csum[nhq[q]][n] += c;
                }
#pragma unroll
    for (int o = 1; o < 16; o <<= 1)
#pragma unroll
        for (int m = 0; m < 2; ++m)
#pragma unroll
            for (int f = 0; f < 4; ++f)
#pragma unroll
                for (int r = 0; r < 4; ++r)
                    rsum[m][f][r] += __shfl_xor(rsum[m][f][r], o, 64);
    if (l15 == 0) {
#pragma unroll
        for (int m = 0; m < 2; ++m)
#pragma unroll
            for (int f = 0; f < 4; ++f)
#pragma unroll
                for (int r = 0; r < 4; ++r)
                    atomicAdd(&rc[bi * 256 + m * 128 + wq * 64 + f * 16 + li4 * 4 + r],
                              rsum[m][f][r]);
    }
    if (!dblk) {
#pragma unroll
        for (int o = 16; o < 64; o <<= 1)
#pragma unroll
            for (int n2 = 0; n2 < 2; ++n2)
#pragma unroll
                for (int n = 0; n < 2; ++n)
                    csum[n2][n] += __shfl_xor(csum[n2][n], o, 64);
        if (li4 == 0) {
#pragma unroll
            for (int n2 = 0; n2 < 2; ++n2)
#pragma unroll
                for (int n = 0; n < 2; ++n)
                    atomicAdd(&rc[bj * 256 + n2 * 128 + wc * 32 + n * 16 + l15],
                              csum[n2][n]);
        }
    }
}

// ---------------------------------------------------------------------------
// k_cubefin: per danger slot, correction = sum_c [(s0+s1+s2)^3 - s0^3]
// (skip c == drow; s0 bitwise-equals the big pass's hh value).
// ---------------------------------------------------------------------------
__global__ __launch_bounds__(256) void k_cubefin(const float* __restrict__ Sb,
                                                 const int* __restrict__ dlist,
                                                 float* __restrict__ rc) {
    const int slot = blockIdx.x;
    const int drow = dlist[slot];
    if (drow < 0) return;
    const int tid = threadIdx.x;
    const float* s0p = Sb + ((size_t)slot << 13);
    const float* s1p = Sb + ((size_t)(256 + slot) << 13);
    const float* s2p = Sb + ((size_t)(512 + slot) << 13);
    float sum = 0.f;
    for (int c = tid; c < VV; c += 256) {
        float s0 = s0p[c];
        float sf = s0 + s1p[c] + s2p[c];
        float d = sf * sf * sf - s0 * s0 * s0;
        if (c == drow) d = 0.f;
        sum += d;
    }
    __shared__ float red[256];
    red[tid] = sum;
    __syncthreads();
    for (int o = 128; o > 0; o >>= 1) {
        if (tid < o) red[tid] += red[tid + o];
        __syncthreads();
    }
    if (tid == 0) atomicAdd(&rc[drow], red[0]);
}

// ---------------------------------------------------------------------------
// k_final: out = collapse + 0.2 * sum_i rc_i / (mnum_i/8191 + 1e-6)
// ---------------------------------------------------------------------------
__global__ __launch_bounds__(256) void k_final(const float* __restrict__ rc,
                                               const double* __restrict__ mnum,
                                               const double* __restrict__ dd,
                                               float* __restrict__ out) {
    int tid = threadIdx.x;
    double acc = 0.0, col = 0.0;
    for (int r = tid; r < VV; r += 256) {
        double m = mnum[r] / 8191.0 + 1e-6;
        acc += (double)rc[r] / m;
        double dm = dd[r] - 1.0;
        col += dm * dm;
    }
    __shared__ double sa[256], sc[256];
    sa[tid] = acc;
    sc[tid] = col;
    __syncthreads();
    for (int o = 128; o > 0; o >>= 1) {
        if (tid < o) {
            sa[tid] += sa[tid + o];
            sc[tid] += sc[tid + o];
        }
        __syncthreads();
    }
    if (tid == 0) out[0] = (float)(sc[0] + 0.2 * sa[0]);
}

// ---------------------------------------------------------------------------
extern "C" void kernel_launch(void* const* d_in, const int* in_sizes, int n_in,
                              void* d_out, int out_size, void* d_ws, size_t ws_size,
                              hipStream_t stream) {
    const float* t = (const float*)d_in[0];
    float* out = (float*)d_out;

    char* ws = (char*)d_ws;
    float* Sb = (float*)ws;  // 3*256*8192*4B = 24 MB
    size_t off = (size_t)VV * DD * sizeof(float);  // keep 25.2 MB region
    ushort* xh = (ushort*)(ws + off); off += (size_t)VV * DD * sizeof(ushort);
    ushort* xl = (ushort*)(ws + off); off += (size_t)VV * DD * sizeof(ushort);
    double* g = (double*)(ws + off);  off += DD * sizeof(double);
    double* mnum = (double*)(ws + off); off += VV * sizeof(double);
    double* dd = (double*)(ws + off);  off += VV * sizeof(double);
    float* rc = (float*)(ws + off);    off += VV * sizeof(float);
    int* dlist = (int*)(ws + off);     off += NDMAX * sizeof(int);
    float* norms = (float*)(ws + off); off += VV * sizeof(float);

    k_normpack<<<VV, 256, 0, stream>>>(t, norms, xh, xl, g, rc);
    k_colsum<<<256, 256, 0, stream>>>(t, norms, g);
    k_mean<<<VV / 4, 256, 0, stream>>>(t, norms, g, mnum, dd);
    k_select<<<1, 256, 0, stream>>>(mnum, dlist);
    k_cube<<<672, 512, 0, stream>>>(xh, xl, dlist, Sb, rc);
    k_cubefin<<<NDMAX, 256, 0, stream>>>(Sb, dlist, rc);
    k_final<<<1, 256, 0, stream>>>(rc, mnum, dd, out);
}